// Round 6
// baseline (377.453 us; speedup 1.0000x reference)
//
#include <hip/hip_runtime.h>
#include <hip/hip_bf16.h>

typedef unsigned short u16;
typedef __bf16 bf16x8 __attribute__((ext_vector_type(8)));
typedef float f32x16 __attribute__((ext_vector_type(16)));

#define MDIM 16384   // 8 * 2048 rows of x
#define NDIM 2048    // output features
#define KDIM 2048    // input features
#define RANK 16
#define BM 256
#define BN 256
#define BK 64
#define NTILE (KDIM / BK)   // 32 K-tiles
#define NITER (NTILE / 2)   // 16 iterations, 2 K-tiles each

// ---- fp32 -> bf16 round-to-nearest-even ----
__device__ __forceinline__ u16 f2bf(float f) {
    union { float f; unsigned u; } v; v.f = f;
    unsigned u = v.u;
    u += 0x7FFFu + ((u >> 16) & 1u);   // RNE
    return (u16)(u >> 16);
}

// ---- async global->LDS, 16B/lane, dest = wave-uniform base + lane*16 ----
__device__ __forceinline__ void async_copy16(const void* gsrc, void* ldst) {
    __builtin_amdgcn_global_load_lds(
        (const __attribute__((address_space(1))) void*)gsrc,
        (__attribute__((address_space(3))) void*)ldst,
        16, 0, 0);
}

// ============================================================
// Kernel 1 (unchanged from round-5 passing version): grid-stride fused
// prep. First T_WITEMS float4-items build w = W + 2*B@A -> bf16;
// remaining items convert x fp32 -> bf16.
// ============================================================
#define T_WITEMS (NDIM * (KDIM / 4))                   // 1,048,576
#define T_ITEMS  ((MDIM + NDIM) * (KDIM / 4))          // 9,437,184
#define PREP_BLOCKS 2048

__global__ __launch_bounds__(256) void prep(const float* __restrict__ x,
                                            const float* __restrict__ W,
                                            const float* __restrict__ Bm,
                                            const float* __restrict__ Am,
                                            u16* __restrict__ xb,
                                            u16* __restrict__ wb) {
    const int stride = PREP_BLOCKS * 256;
    for (int t = blockIdx.x * 256 + threadIdx.x; t < T_ITEMS; t += stride) {
        if (t < T_WITEMS) {
            int o  = t >> 9;                    // / (KDIM/4)
            int dq = t & 511;                   // float4 index within row
            float4 acc = ((const float4*)W)[(size_t)o * (KDIM / 4) + dq];
            const float* Bo = Bm + (size_t)o * RANK;
#pragma unroll
            for (int r = 0; r < RANK; ++r) {
                float bv = 2.0f * Bo[r];        // ALPHA/RANK = 2
                float4 a4 = ((const float4*)(Am + (size_t)r * KDIM))[dq];
                acc.x += bv * a4.x; acc.y += bv * a4.y;
                acc.z += bv * a4.z; acc.w += bv * a4.w;
            }
            ushort4 ov;
            ov.x = f2bf(acc.x); ov.y = f2bf(acc.y);
            ov.z = f2bf(acc.z); ov.w = f2bf(acc.w);
            ((ushort4*)wb)[t] = ov;
        } else {
            int ti = t - T_WITEMS;              // 0 .. MDIM*KDIM/4-1
            float4 v = ((const float4*)x)[ti];
            ushort4 o;
            o.x = f2bf(v.x); o.y = f2bf(v.y); o.z = f2bf(v.z); o.w = f2bf(v.w);
            ((ushort4*)xb)[ti] = o;
        }
    }
}

// ============================================================
// Kernel 2: SAME 8-phase/counted-vmcnt schedule as the round-2/5
// passing kernel (barriers, STG placement, vmcnt ledger byte-identical),
// but MFMA shape switched 16x16x32 -> 32x32x16 (2382 vs 2075 TF ubench;
// 64 instead of 128 MFMA issues per iteration, same FLOPs).
// Fragment maps:
//   A/B operand: row/col = lane&31; k-chunk(8 bf16) = s*2 + (lane>>5);
//                LDS slot = chunk ^ (row&7), row&7 == lane&7.
//   C/D (m74/m101 verified): col = lane&31,
//                row = (reg&3) + 8*(reg>>2) + 4*(lane>>5), reg 0..15.
// Register footprint identical (af 16 + bf 32 + acc 128 VGPR).
// ============================================================
__global__ __launch_bounds__(512, 2) void gemm_bt(const u16* __restrict__ xb,
                                                  const u16* __restrict__ wb,
                                                  const float* __restrict__ bias,
                                                  float* __restrict__ out) {
    __shared__ __align__(16) u16 lds[2][2][BM * BK];   // [buf][A|B][256*64] = 128 KiB

    const int tid  = threadIdx.x;
    const int lane = tid & 63;
    const int w    = tid >> 6;          // wave 0..7
    const int wm   = w >> 2;            // 0..1 (row half of C tile)
    const int wn   = w & 3;             // 0..3 (col quarter)

    // XCD-aware bijective swizzle: 512 blocks, 512 % 8 == 0
    const int bid = blockIdx.x;
    const int wg  = (bid & 7) * (512 / 8) + (bid >> 3);
    const int m0  = (wg >> 3) * BM;     // 64 m-tiles
    const int n0  = (wg & 7) * BN;      // 8 n-tiles

    // staging geometry: one STG = 8 waves x 64 lanes x 16B = 64 rows of 128B
    const int srow   = lane >> 3;                 // row within wave's 8-row chunk
    const int schunk = (lane & 7) ^ srow;         // permuted global chunk
    const int selem  = schunk * 8;                // bf16 offset within row
    const int grow   = w * 8 + srow;              // row within 64-row chunk

    // fragment geometry (32x32x16)
    const int l31   = lane & 31;
    const int khalf = lane >> 5;        // k-half selector
    const int swz7  = lane & 7;         // == row&7 for all A/B fragment rows

    int coff[4];
#pragma unroll
    for (int s = 0; s < 4; ++s)
        coff[s] = (((s * 2 + khalf) ^ swz7) << 3);   // bf16 elems within row

    int arow[4], brow[2];
#pragma unroll
    for (int q = 0; q < 4; ++q) arow[q] = (wm * 128 + q * 32 + l31) * BK;
#pragma unroll
    for (int c = 0; c < 2; ++c) brow[c] = (wn * 64 + c * 32 + l31) * BK;

    u16* As0 = &lds[0][0][0];
    u16* Bs0 = &lds[0][1][0];
    u16* As1 = &lds[1][0][0];
    u16* Bs1 = &lds[1][1][0];

    const u16* ga = xb + (size_t)m0 * KDIM;
    const u16* gb = wb + (size_t)n0 * KDIM;

#define STG(dstbase, gsrc, rb, kk)                                             \
    async_copy16((gsrc) + (size_t)((rb) + grow) * KDIM + (size_t)(kk) + selem, \
                 (char*)(dstbase) + ((rb) + w * 8) * (BK * 2))

#define BAR do { asm volatile("" ::: "memory");                   \
                 __builtin_amdgcn_s_barrier();                    \
                 asm volatile("" ::: "memory"); } while (0)
#define LGK0 asm volatile("s_waitcnt lgkmcnt(0)" ::: "memory")
#define VM4  asm volatile("s_waitcnt vmcnt(4)" ::: "memory")

// read A fragments: row-tiles qb..qb+1, k-steps sb..sb+1
#define READ_A(base, qb, sb)                                                   \
    _Pragma("unroll")                                                          \
    for (int qq = 0; qq < 2; ++qq)                                             \
        _Pragma("unroll")                                                      \
        for (int s2 = 0; s2 < 2; ++s2)                                         \
            af[qq][s2] = *(const bf16x8*)((base) + arow[(qb) + qq] + coff[(sb) + s2]);

// read all B fragments for this K-tile: 2 col-tiles x 4 k-steps
#define READ_B(base)                                                           \
    _Pragma("unroll")                                                          \
    for (int ct = 0; ct < 2; ++ct)                                             \
        _Pragma("unroll")                                                      \
        for (int s = 0; s < 4; ++s)                                            \
            bf[ct][s] = *(const bf16x8*)((base) + brow[ct] + coff[s]);

// 8 MFMAs: row-tiles qb..qb+1 x 2 col-tiles x k-steps sb..sb+1.
// s2-outer: 4 independent (qq,ct) chains per s2 group.
#define MFMA8(qb, sb) do {                                                     \
    __builtin_amdgcn_s_setprio(1);                                             \
    _Pragma("unroll")                                                          \
    for (int s2 = 0; s2 < 2; ++s2)                                             \
        _Pragma("unroll")                                                      \
        for (int ct = 0; ct < 2; ++ct)                                         \
            _Pragma("unroll")                                                  \
            for (int qq = 0; qq < 2; ++qq)                                     \
                acc[(qb) + qq][ct] = __builtin_amdgcn_mfma_f32_32x32x16_bf16(  \
                    af[qq][s2], bf[ct][(sb) + s2], acc[(qb) + qq][ct], 0, 0, 0);\
    __builtin_amdgcn_s_setprio(0);                                             \
} while (0)

    // ---- prologue: tile0 A+B -> buf0 (8 loads), B(tile1) -> buf1 (4 loads)
    STG(As0, ga, 0, 0); STG(As0, ga, 64, 0); STG(As0, ga, 128, 0); STG(As0, ga, 192, 0);
    STG(Bs0, gb, 0, 0); STG(Bs0, gb, 64, 0); STG(Bs0, gb, 128, 0); STG(Bs0, gb, 192, 0);
    STG(Bs1, gb, 0, BK); STG(Bs1, gb, 64, BK); STG(Bs1, gb, 128, BK); STG(Bs1, gb, 192, BK);

    f32x16 acc[4][2];
#pragma unroll
    for (int q = 0; q < 4; ++q)
#pragma unroll
        for (int ct = 0; ct < 2; ++ct)
#pragma unroll
            for (int r = 0; r < 16; ++r)
                acc[q][ct][r] = 0.f;

    bf16x8 af[2][2], bf[2][4];

    VM4;   // tile0's 8 loads landed; B(1)'s 4 still in flight
    BAR;

#pragma unroll 1
    for (int it = 0; it < NITER; ++it) {
        const int t   = 2 * it;
        const int ka1 = (t + 1) * BK;                  // <= 31*64, never wraps
        const int kb2 = ((t + 2) & (NTILE - 1)) * BK;  // wraps harmlessly at tail
        const int kb3 = ((t + 3) & (NTILE - 1)) * BK;

        // ---- P1: tile t (buf0): B all + A(q01,s01); stage A(t+1)->buf1 ----
        READ_B(Bs0); READ_A(As0, 0, 0);
        STG(As1, ga, 0, ka1); STG(As1, ga, 64, ka1);
        STG(As1, ga, 128, ka1); STG(As1, ga, 192, ka1);
        BAR; LGK0; MFMA8(0, 0); BAR;

        // ---- P2: A(q01,s23); stage B(t+2) rows 0-127 -> buf0 ----
        READ_A(As0, 0, 2);
        STG(Bs0, gb, 0, kb2); STG(Bs0, gb, 64, kb2);
        BAR; LGK0; MFMA8(0, 2); BAR;

        // ---- P3: A(q23,s01); stage B(t+2) rows 128-255 -> buf0 ----
        READ_A(As0, 2, 0);
        STG(Bs0, gb, 128, kb2); STG(Bs0, gb, 192, kb2);
        BAR; LGK0; MFMA8(2, 0); BAR;

        // ---- P4: A(q23,s23); counted wait ----
        READ_A(As0, 2, 2);
        BAR; LGK0; MFMA8(2, 2);
        VM4;   // A(t+1), B(t+1) landed; B(t+2) (4 loads) stays in flight
        BAR;

        // ---- P5: tile t+1 (buf1): B all + A(q01,s01); stage A(t+2)->buf0 ----
        READ_B(Bs1); READ_A(As1, 0, 0);
        STG(As0, ga, 0, kb2); STG(As0, ga, 64, kb2);
        STG(As0, ga, 128, kb2); STG(As0, ga, 192, kb2);
        BAR; LGK0; MFMA8(0, 0); BAR;

        // ---- P6: A(q01,s23); stage B(t+3) rows 0-127 -> buf1 ----
        READ_A(As1, 0, 2);
        STG(Bs1, gb, 0, kb3); STG(Bs1, gb, 64, kb3);
        BAR; LGK0; MFMA8(0, 2); BAR;

        // ---- P7: A(q23,s01); stage B(t+3) rows 128-255 -> buf1 ----
        READ_A(As1, 2, 0);
        STG(Bs1, gb, 128, kb3); STG(Bs1, gb, 192, kb3);
        BAR; LGK0; MFMA8(2, 0); BAR;

        // ---- P8: A(q23,s23); counted wait ----
        READ_A(As1, 2, 2);
        BAR; LGK0; MFMA8(2, 2);
        VM4;   // A(t+2), B(t+2) landed; B(t+3) stays in flight
        BAR;
    }

    // ---- epilogue: 32x32 C/D layout (m74/m101 verified):
    // col = lane&31, row = (reg&3) + 8*(reg>>2) + 4*(lane>>5)
#pragma unroll
    for (int ct = 0; ct < 2; ++ct) {
        const int col = n0 + wn * 64 + ct * 32 + l31;
        const float bj = bias[col];
#pragma unroll
        for (int q = 0; q < 4; ++q) {
            const int rowb = m0 + wm * 128 + q * 32 + 4 * khalf;
#pragma unroll
            for (int r = 0; r < 16; ++r) {
                const int row = rowb + (r & 3) + 8 * (r >> 2);
                out[(size_t)row * NDIM + col] = acc[q][ct][r] + bj;
            }
        }
    }

#undef STG
#undef BAR
#undef LGK0
#undef VM4
#undef READ_A
#undef READ_B
#undef MFMA8
}

extern "C" void kernel_launch(void* const* d_in, const int* in_sizes, int n_in,
                              void* d_out, int out_size, void* d_ws, size_t ws_size,
                              hipStream_t stream) {
    const float* x    = (const float*)d_in[0];   // [8,2048,2048]
    const float* W    = (const float*)d_in[1];   // [2048,2048] row-major [o,d]
    const float* bias = (const float*)d_in[2];   // [2048]
    const float* Bm   = (const float*)d_in[3];   // [2048,16]
    const float* Am   = (const float*)d_in[4];   // [16,2048]
    float* out = (float*)d_out;

    u16* xb   = (u16*)d_ws;                      // 16384*2048 bf16 = 64 MB
    u16* wbuf = xb + (size_t)MDIM * KDIM;        // 2048*2048 bf16 = 8 MB

    prep<<<PREP_BLOCKS, 256, 0, stream>>>(x, W, Bm, Am, xb, wbuf);

    dim3 grid((MDIM / BM) * (NDIM / BN));        // 512 blocks
    gemm_bt<<<grid, 512, 0, stream>>>(xb, wbuf, bias, out);
}

// Round 8
// 368.144 us; speedup vs baseline: 1.0253x; 1.0253x over previous
//
#include <hip/hip_runtime.h>
#include <hip/hip_bf16.h>

typedef unsigned short u16;
typedef __bf16 bf16x8 __attribute__((ext_vector_type(8)));
typedef float f32x4 __attribute__((ext_vector_type(4)));

#define MDIM 16384   // 8 * 2048 rows of x
#define NDIM 2048    // output features
#define KDIM 2048    // input features
#define RANK 16
#define BM 256
#define BN 256
#define BK 64
#define NTILE (KDIM / BK)   // 32 K-tiles
#define NITER (NTILE / 2)   // 16 iterations, 2 K-tiles each

// ---- fp32 -> bf16 round-to-nearest-even ----
__device__ __forceinline__ u16 f2bf(float f) {
    union { float f; unsigned u; } v; v.f = f;
    unsigned u = v.u;
    u += 0x7FFFu + ((u >> 16) & 1u);   // RNE
    return (u16)(u >> 16);
}

// ---- async global->LDS, 16B/lane, dest = wave-uniform base + lane*16 ----
__device__ __forceinline__ void async_copy16(const void* gsrc, void* ldst) {
    __builtin_amdgcn_global_load_lds(
        (const __attribute__((address_space(1))) void*)gsrc,
        (__attribute__((address_space(3))) void*)ldst,
        16, 0, 0);
}

// ============================================================
// Kernel 1 (unchanged, passing): grid-stride fused prep.
// First T_WITEMS float4-items build w = W + 2*B@A -> bf16;
// remaining items convert x fp32 -> bf16.
// ============================================================
#define T_WITEMS (NDIM * (KDIM / 4))                   // 1,048,576
#define T_ITEMS  ((MDIM + NDIM) * (KDIM / 4))          // 9,437,184
#define PREP_BLOCKS 2048

__global__ __launch_bounds__(256) void prep(const float* __restrict__ x,
                                            const float* __restrict__ W,
                                            const float* __restrict__ Bm,
                                            const float* __restrict__ Am,
                                            u16* __restrict__ xb,
                                            u16* __restrict__ wb) {
    const int stride = PREP_BLOCKS * 256;
    for (int t = blockIdx.x * 256 + threadIdx.x; t < T_ITEMS; t += stride) {
        if (t < T_WITEMS) {
            int o  = t >> 9;                    // / (KDIM/4)
            int dq = t & 511;                   // float4 index within row
            float4 acc = ((const float4*)W)[(size_t)o * (KDIM / 4) + dq];
            const float* Bo = Bm + (size_t)o * RANK;
#pragma unroll
            for (int r = 0; r < RANK; ++r) {
                float bv = 2.0f * Bo[r];        // ALPHA/RANK = 2
                float4 a4 = ((const float4*)(Am + (size_t)r * KDIM))[dq];
                acc.x += bv * a4.x; acc.y += bv * a4.y;
                acc.z += bv * a4.z; acc.w += bv * a4.w;
            }
            ushort4 ov;
            ov.x = f2bf(acc.x); ov.y = f2bf(acc.y);
            ov.z = f2bf(acc.z); ov.w = f2bf(acc.w);
            ((ushort4*)wb)[t] = ov;
        } else {
            int ti = t - T_WITEMS;              // 0 .. MDIM*KDIM/4-1
            float4 v = ((const float4*)x)[ti];
            ushort4 o;
            o.x = f2bf(v.x); o.y = f2bf(v.y); o.z = f2bf(v.z); o.w = f2bf(v.w);
            ((ushort4*)xb)[ti] = o;
        }
    }
}

// ============================================================
// Kernel 2: round-5 PASSING 16x16x32 kernel (137.7us, 0 bank
// conflicts) with the redundant pre-MFMA barrier and explicit
// lgkmcnt(0) removed: phase = reads; STG; MFMA (compiler emits
// fine-grained lgkmcnt per operand); [VM4]; BAR.
//
// Safety audit (resubmission after infra-signature failure):
//  - Hang: impossible — uniform barrier path, satisfiable waits.
//  - Overwrite hazards: STG into region R is issued only after the
//    barrier that follows the phase whose MFMA consumed R's reads
//    (compiler lgkmcnt drains reads before MFMA; wave reaches BAR
//    after MFMA; STG issues after BAR; its LDS write lands after
//    issue). P1rd(Bs0)/P2stg(Bs0): BAR(P1). P4rd(As0)/P5stg(As0):
//    BAR(P4). P5rd(Bs1)/P6stg(Bs1): BAR(P5) (+frags in regs).
//  - Staging visibility: VM4 at P4/P8 retires exactly the 8 loads
//    (B(t+1)+A(t+1) / B(t+2)+A(t+2)) read in the next half-iter;
//    following BAR globalizes. Ledger: 4 ->8 ->10 ->12 -VM4-> 4.
//  - "memory" clobbers pin loads/STG to their phase.
// ============================================================
__global__ __launch_bounds__(512, 2) void gemm_bt(const u16* __restrict__ xb,
                                                  const u16* __restrict__ wb,
                                                  const float* __restrict__ bias,
                                                  float* __restrict__ out) {
    __shared__ __align__(16) u16 lds[2][2][BM * BK];   // [buf][A|B][256*64] = 128 KiB

    const int tid  = threadIdx.x;
    const int lane = tid & 63;
    const int w    = tid >> 6;          // wave 0..7
    const int wm   = w >> 2;            // 0..1 (row half of C tile)
    const int wn   = w & 3;             // 0..3 (col quarter)

    // XCD-aware bijective swizzle: 512 blocks, 512 % 8 == 0
    const int bid = blockIdx.x;
    const int wg  = (bid & 7) * (512 / 8) + (bid >> 3);
    const int m0  = (wg >> 3) * BM;     // 64 m-tiles
    const int n0  = (wg & 7) * BN;      // 8 n-tiles

    // staging geometry: one STG = 8 waves x 64 lanes x 16B = 64 rows of 128B
    const int srow   = lane >> 3;                 // row within wave's 8-row chunk
    const int schunk = (lane & 7) ^ srow;         // permuted global chunk
    const int selem  = schunk * 8;                // bf16 offset within row
    const int grow   = w * 8 + srow;              // row within 64-row chunk

    const int quad = lane >> 4;
    const int l16  = lane & 15;
    const int swz  = l16 & 7;
    const int coff0 = ((0 * 4 + quad) ^ swz) << 3;   // kstep 0 chunk offset (elems)
    const int coff1 = ((1 * 4 + quad) ^ swz) << 3;   // kstep 1

    int arow[8], brow[4];
#pragma unroll
    for (int f = 0; f < 8; ++f) arow[f] = (wm * 128 + f * 16 + l16) * BK;
#pragma unroll
    for (int j = 0; j < 4; ++j) brow[j] = (wn * 64 + j * 16 + l16) * BK;

    u16* As0 = &lds[0][0][0];
    u16* Bs0 = &lds[0][1][0];
    u16* As1 = &lds[1][0][0];
    u16* Bs1 = &lds[1][1][0];

    const u16* ga = xb + (size_t)m0 * KDIM;
    const u16* gb = wb + (size_t)n0 * KDIM;

#define STG(dstbase, gsrc, rb, kk)                                             \
    async_copy16((gsrc) + (size_t)((rb) + grow) * KDIM + (size_t)(kk) + selem, \
                 (char*)(dstbase) + ((rb) + w * 8) * (BK * 2))

#define BAR do { asm volatile("" ::: "memory");                   \
                 __builtin_amdgcn_s_barrier();                    \
                 asm volatile("" ::: "memory"); } while (0)
#define VM4  asm volatile("s_waitcnt vmcnt(4)" ::: "memory")

#define LDA_QUAD(base, q)                                                      \
    _Pragma("unroll")                                                          \
    for (int i = 0; i < 2; ++i) {                                              \
        af[i][0] = *(const bf16x8*)((base) + arow[(q) * 2 + i] + coff0);       \
        af[i][1] = *(const bf16x8*)((base) + arow[(q) * 2 + i] + coff1);       \
    }

#define LDB_ALL(base)                                                          \
    _Pragma("unroll")                                                          \
    for (int j = 0; j < 4; ++j) {                                              \
        bf[j][0] = *(const bf16x8*)((base) + brow[j] + coff0);                 \
        bf[j][1] = *(const bf16x8*)((base) + brow[j] + coff1);                 \
    }

// 16 MFMAs: quadrant q (rowfrags 2q,2q+1) x 4 colfrags x 2 ksteps.
#define MFMA16(q) do {                                                         \
    __builtin_amdgcn_s_setprio(1);                                             \
    _Pragma("unroll")                                                          \
    for (int s = 0; s < 2; ++s)                                                \
        _Pragma("unroll")                                                      \
        for (int j = 0; j < 4; ++j)                                            \
            _Pragma("unroll")                                                  \
            for (int i = 0; i < 2; ++i)                                        \
                acc[(q) * 2 + i][j] = __builtin_amdgcn_mfma_f32_16x16x32_bf16( \
                    af[i][s], bf[j][s], acc[(q) * 2 + i][j], 0, 0, 0);         \
    __builtin_amdgcn_s_setprio(0);                                             \
} while (0)

    // ---- prologue: tile0 A+B -> buf0 (8 loads), B(tile1) -> buf1 (4 loads)
    STG(As0, ga, 0, 0); STG(As0, ga, 64, 0); STG(As0, ga, 128, 0); STG(As0, ga, 192, 0);
    STG(Bs0, gb, 0, 0); STG(Bs0, gb, 64, 0); STG(Bs0, gb, 128, 0); STG(Bs0, gb, 192, 0);
    STG(Bs1, gb, 0, BK); STG(Bs1, gb, 64, BK); STG(Bs1, gb, 128, BK); STG(Bs1, gb, 192, BK);

    f32x4 acc[8][4];
#pragma unroll
    for (int i = 0; i < 8; ++i)
#pragma unroll
        for (int j = 0; j < 4; ++j)
            acc[i][j] = (f32x4){0.f, 0.f, 0.f, 0.f};

    bf16x8 af[2][2], bf[4][2];

    VM4;   // tile0's 8 loads landed; B(1)'s 4 still in flight
    BAR;

#pragma unroll 1
    for (int it = 0; it < NITER; ++it) {
        const int t   = 2 * it;
        const int ka1 = (t + 1) * BK;                  // <= 31*64, never wraps
        const int kb2 = ((t + 2) & (NTILE - 1)) * BK;  // wraps harmlessly at tail
        const int kb3 = ((t + 3) & (NTILE - 1)) * BK;

        // ---- P1: tile t (buf0): B all + A quad0; stage A(t+1)->buf1 ----
        LDB_ALL(Bs0); LDA_QUAD(As0, 0);
        STG(As1, ga, 0, ka1); STG(As1, ga, 64, ka1);
        STG(As1, ga, 128, ka1); STG(As1, ga, 192, ka1);
        MFMA16(0); BAR;

        // ---- P2: A quad1; stage B(t+2) rows 0-127 -> buf0 ----
        LDA_QUAD(As0, 1);
        STG(Bs0, gb, 0, kb2); STG(Bs0, gb, 64, kb2);
        MFMA16(1); BAR;

        // ---- P3: A quad2; stage B(t+2) rows 128-255 -> buf0 ----
        LDA_QUAD(As0, 2);
        STG(Bs0, gb, 128, kb2); STG(Bs0, gb, 192, kb2);
        MFMA16(2); BAR;

        // ---- P4: A quad3; counted wait ----
        LDA_QUAD(As0, 3);
        MFMA16(3);
        VM4;   // A(t+1), B(t+1) landed; B(t+2) (4 loads) stays in flight
        BAR;

        // ---- P5: tile t+1 (buf1): B all + A quad0; stage A(t+2)->buf0 ----
        LDB_ALL(Bs1); LDA_QUAD(As1, 0);
        STG(As0, ga, 0, kb2); STG(As0, ga, 64, kb2);
        STG(As0, ga, 128, kb2); STG(As0, ga, 192, kb2);
        MFMA16(0); BAR;

        // ---- P6: A quad1; stage B(t+3) rows 0-127 -> buf1 ----
        LDA_QUAD(As1, 1);
        STG(Bs1, gb, 0, kb3); STG(Bs1, gb, 64, kb3);
        MFMA16(1); BAR;

        // ---- P7: A quad2; stage B(t+3) rows 128-255 -> buf1 ----
        LDA_QUAD(As1, 2);
        STG(Bs1, gb, 128, kb3); STG(Bs1, gb, 192, kb3);
        MFMA16(2); BAR;

        // ---- P8: A quad3; counted wait ----
        LDA_QUAD(As1, 3);
        MFMA16(3);
        VM4;   // A(t+2), B(t+2) landed; B(t+3) stays in flight
        BAR;
    }

    // ---- epilogue: C/D layout col=lane&15, row=quad*4+reg (verified) ----
#pragma unroll
    for (int j = 0; j < 4; ++j) {
        const int col = n0 + wn * 64 + j * 16 + l16;
        const float bj = bias[col];
#pragma unroll
        for (int f = 0; f < 8; ++f) {
            const int rowb = m0 + wm * 128 + f * 16 + quad * 4;
#pragma unroll
            for (int r = 0; r < 4; ++r)
                out[(size_t)(rowb + r) * NDIM + col] = acc[f][j][r] + bj;
        }
    }

#undef STG
#undef BAR
#undef VM4
#undef LDA_QUAD
#undef LDB_ALL
#undef MFMA16
}

extern "C" void kernel_launch(void* const* d_in, const int* in_sizes, int n_in,
                              void* d_out, int out_size, void* d_ws, size_t ws_size,
                              hipStream_t stream) {
    const float* x    = (const float*)d_in[0];   // [8,2048,2048]
    const float* W    = (const float*)d_in[1];   // [2048,2048] row-major [o,d]
    const float* bias = (const float*)d_in[2];   // [2048]
    const float* Bm   = (const float*)d_in[3];   // [2048,16]
    const float* Am   = (const float*)d_in[4];   // [16,2048]
    float* out = (float*)d_out;

    u16* xb   = (u16*)d_ws;                      // 16384*2048 bf16 = 64 MB
    u16* wbuf = xb + (size_t)MDIM * KDIM;        // 2048*2048 bf16 = 8 MB

    prep<<<PREP_BLOCKS, 256, 0, stream>>>(x, W, Bm, Am, xb, wbuf);

    dim3 grid((MDIM / BM) * (NDIM / BN));        // 512 blocks
    gemm_bt<<<grid, 512, 0, stream>>>(xb, wbuf, bias, out);
}

// Round 9
// 367.906 us; speedup vs baseline: 1.0259x; 1.0006x over previous
//
#include <hip/hip_runtime.h>
#include <hip/hip_bf16.h>

typedef unsigned short u16;
typedef __bf16 bf16x8 __attribute__((ext_vector_type(8)));
typedef float f32x4 __attribute__((ext_vector_type(4)));

#define MDIM 16384   // 8 * 2048 rows of x
#define NDIM 2048    // output features
#define KDIM 2048    // input features
#define RANK 16
#define BM 256
#define BN 256
#define BK 64
#define NTILE (KDIM / BK)   // 32 K-tiles
#define NITER (NTILE / 2)   // 16 iterations, 2 K-tiles each

// ---- fp32 -> bf16 round-to-nearest-even ----
__device__ __forceinline__ u16 f2bf(float f) {
    union { float f; unsigned u; } v; v.f = f;
    unsigned u = v.u;
    u += 0x7FFFu + ((u >> 16) & 1u);   // RNE
    return (u16)(u >> 16);
}

// ---- async global->LDS, 16B/lane, dest = wave-uniform base + lane*16 ----
__device__ __forceinline__ void async_copy16(const void* gsrc, void* ldst) {
    __builtin_amdgcn_global_load_lds(
        (const __attribute__((address_space(1))) void*)gsrc,
        (__attribute__((address_space(3))) void*)ldst,
        16, 0, 0);
}

// ============================================================
// Kernel 1 (unchanged, passing): grid-stride fused prep.
// ============================================================
#define T_WITEMS (NDIM * (KDIM / 4))                   // 1,048,576
#define T_ITEMS  ((MDIM + NDIM) * (KDIM / 4))          // 9,437,184
#define PREP_BLOCKS 2048

__global__ __launch_bounds__(256) void prep(const float* __restrict__ x,
                                            const float* __restrict__ W,
                                            const float* __restrict__ Bm,
                                            const float* __restrict__ Am,
                                            u16* __restrict__ xb,
                                            u16* __restrict__ wb) {
    const int stride = PREP_BLOCKS * 256;
    for (int t = blockIdx.x * 256 + threadIdx.x; t < T_ITEMS; t += stride) {
        if (t < T_WITEMS) {
            int o  = t >> 9;                    // / (KDIM/4)
            int dq = t & 511;                   // float4 index within row
            float4 acc = ((const float4*)W)[(size_t)o * (KDIM / 4) + dq];
            const float* Bo = Bm + (size_t)o * RANK;
#pragma unroll
            for (int r = 0; r < RANK; ++r) {
                float bv = 2.0f * Bo[r];        // ALPHA/RANK = 2
                float4 a4 = ((const float4*)(Am + (size_t)r * KDIM))[dq];
                acc.x += bv * a4.x; acc.y += bv * a4.y;
                acc.z += bv * a4.z; acc.w += bv * a4.w;
            }
            ushort4 ov;
            ov.x = f2bf(acc.x); ov.y = f2bf(acc.y);
            ov.z = f2bf(acc.z); ov.w = f2bf(acc.w);
            ((ushort4*)wb)[t] = ov;
        } else {
            int ti = t - T_WITEMS;              // 0 .. MDIM*KDIM/4-1
            float4 v = ((const float4*)x)[ti];
            ushort4 o;
            o.x = f2bf(v.x); o.y = f2bf(v.y); o.z = f2bf(v.z); o.w = f2bf(v.w);
            ((ushort4*)xb)[ti] = o;
        }
    }
}

// ============================================================
// Kernel 2: round-8 PASSING kernel (126.5us, MfmaUtil 47, 0 conflicts)
// with barriers thinned 8 -> 4 per iteration (the minimum the hazard
// graph supports). Merged phases let 48 MFMAs run uninterrupted and
// q2/q3 reads overlap MFMA(q1) under compiler lgkmcnt.
//
// Per-iteration structure (tiles t=2I in buf0, t+1 in buf1):
//  Ph1: LDB_ALL(Bs0), LDA(As0,q0); STG A(t+1)->As1 x4; MFMA16(0); BAR
//       (BAR frees Bs0: all waves' B(t) reads consumed by MFMA16(0))
//  Ph2: LDA q1,q2,q3 interleaved with STG B(t+2)->Bs0 x4 and
//       MFMA16(1),(2),(3); VM4; BAR
//       (VM4 retires B(t+1)+A(t+1), read in Ph3; BAR frees As0+globalizes)
//  Ph3: LDB_ALL(Bs1), LDA(As1,q0); STG A(t+2)->As0 x4; MFMA16(0); BAR
//  Ph4: LDA q1,q2,q3 + STG B(t+3)->Bs1 x4 + MFMA16(1..3); VM4; BAR
// vmcnt ledger (identical to r8): enter 4 -> Ph1 8 -> Ph2 12 -VM4-> 4
// -> Ph3 8 -> Ph4 12 -VM4-> 4. Every VM4 retires exactly the 8 loads
// read in the following phase; every LDS region's overwrite is >= 1
// barrier after its last read.
// ============================================================
__global__ __launch_bounds__(512, 2) void gemm_bt(const u16* __restrict__ xb,
                                                  const u16* __restrict__ wb,
                                                  const float* __restrict__ bias,
                                                  float* __restrict__ out) {
    __shared__ __align__(16) u16 lds[2][2][BM * BK];   // [buf][A|B][256*64] = 128 KiB

    const int tid  = threadIdx.x;
    const int lane = tid & 63;
    const int w    = tid >> 6;          // wave 0..7
    const int wm   = w >> 2;            // 0..1 (row half of C tile)
    const int wn   = w & 3;             // 0..3 (col quarter)

    // XCD-aware bijective swizzle: 512 blocks, 512 % 8 == 0
    const int bid = blockIdx.x;
    const int wg  = (bid & 7) * (512 / 8) + (bid >> 3);
    const int m0  = (wg >> 3) * BM;     // 64 m-tiles
    const int n0  = (wg & 7) * BN;      // 8 n-tiles

    // staging geometry: one STG = 8 waves x 64 lanes x 16B = 64 rows of 128B
    const int srow   = lane >> 3;                 // row within wave's 8-row chunk
    const int schunk = (lane & 7) ^ srow;         // permuted global chunk
    const int selem  = schunk * 8;                // bf16 offset within row
    const int grow   = w * 8 + srow;              // row within 64-row chunk

    const int quad = lane >> 4;
    const int l16  = lane & 15;
    const int swz  = l16 & 7;
    const int coff0 = ((0 * 4 + quad) ^ swz) << 3;   // kstep 0 chunk offset (elems)
    const int coff1 = ((1 * 4 + quad) ^ swz) << 3;   // kstep 1

    int arow[8], brow[4];
#pragma unroll
    for (int f = 0; f < 8; ++f) arow[f] = (wm * 128 + f * 16 + l16) * BK;
#pragma unroll
    for (int j = 0; j < 4; ++j) brow[j] = (wn * 64 + j * 16 + l16) * BK;

    u16* As0 = &lds[0][0][0];
    u16* Bs0 = &lds[0][1][0];
    u16* As1 = &lds[1][0][0];
    u16* Bs1 = &lds[1][1][0];

    const u16* ga = xb + (size_t)m0 * KDIM;
    const u16* gb = wb + (size_t)n0 * KDIM;

#define STG(dstbase, gsrc, rb, kk)                                             \
    async_copy16((gsrc) + (size_t)((rb) + grow) * KDIM + (size_t)(kk) + selem, \
                 (char*)(dstbase) + ((rb) + w * 8) * (BK * 2))

#define BAR do { asm volatile("" ::: "memory");                   \
                 __builtin_amdgcn_s_barrier();                    \
                 asm volatile("" ::: "memory"); } while (0)
#define VM4  asm volatile("s_waitcnt vmcnt(4)" ::: "memory")

#define LDA_QUAD(base, q)                                                      \
    _Pragma("unroll")                                                          \
    for (int i = 0; i < 2; ++i) {                                              \
        af[i][0] = *(const bf16x8*)((base) + arow[(q) * 2 + i] + coff0);       \
        af[i][1] = *(const bf16x8*)((base) + arow[(q) * 2 + i] + coff1);       \
    }

#define LDB_ALL(base)                                                          \
    _Pragma("unroll")                                                          \
    for (int j = 0; j < 4; ++j) {                                              \
        bf[j][0] = *(const bf16x8*)((base) + brow[j] + coff0);                 \
        bf[j][1] = *(const bf16x8*)((base) + brow[j] + coff1);                 \
    }

// 16 MFMAs: quadrant q (rowfrags 2q,2q+1) x 4 colfrags x 2 ksteps.
#define MFMA16(q) do {                                                         \
    __builtin_amdgcn_s_setprio(1);                                             \
    _Pragma("unroll")                                                          \
    for (int s = 0; s < 2; ++s)                                                \
        _Pragma("unroll")                                                      \
        for (int j = 0; j < 4; ++j)                                            \
            _Pragma("unroll")                                                  \
            for (int i = 0; i < 2; ++i)                                        \
                acc[(q) * 2 + i][j] = __builtin_amdgcn_mfma_f32_16x16x32_bf16( \
                    af[i][s], bf[j][s], acc[(q) * 2 + i][j], 0, 0, 0);         \
    __builtin_amdgcn_s_setprio(0);                                             \
} while (0)

    // ---- prologue: tile0 A+B -> buf0 (8 loads), B(tile1) -> buf1 (4 loads)
    STG(As0, ga, 0, 0); STG(As0, ga, 64, 0); STG(As0, ga, 128, 0); STG(As0, ga, 192, 0);
    STG(Bs0, gb, 0, 0); STG(Bs0, gb, 64, 0); STG(Bs0, gb, 128, 0); STG(Bs0, gb, 192, 0);
    STG(Bs1, gb, 0, BK); STG(Bs1, gb, 64, BK); STG(Bs1, gb, 128, BK); STG(Bs1, gb, 192, BK);

    f32x4 acc[8][4];
#pragma unroll
    for (int i = 0; i < 8; ++i)
#pragma unroll
        for (int j = 0; j < 4; ++j)
            acc[i][j] = (f32x4){0.f, 0.f, 0.f, 0.f};

    bf16x8 af[2][2], bf[4][2];

    VM4;   // tile0's 8 loads landed; B(1)'s 4 still in flight
    BAR;

#pragma unroll 1
    for (int it = 0; it < NITER; ++it) {
        const int t   = 2 * it;
        const int ka1 = (t + 1) * BK;                  // <= 31*64, never wraps
        const int kb2 = ((t + 2) & (NTILE - 1)) * BK;  // wraps harmlessly at tail
        const int kb3 = ((t + 3) & (NTILE - 1)) * BK;

        // ---- Ph1: tile t (buf0): B all + A quad0; stage A(t+1)->buf1 ----
        LDB_ALL(Bs0); LDA_QUAD(As0, 0);
        STG(As1, ga, 0, ka1); STG(As1, ga, 64, ka1);
        STG(As1, ga, 128, ka1); STG(As1, ga, 192, ka1);
        MFMA16(0);
        BAR;   // frees Bs0 (all waves consumed B(t) via MFMA16(0))

        // ---- Ph2: A quads 1-3; stage B(t+2)->Bs0; 48 MFMAs; VM4 ----
        LDA_QUAD(As0, 1);
        STG(Bs0, gb, 0, kb2); STG(Bs0, gb, 64, kb2);
        MFMA16(1);
        LDA_QUAD(As0, 2);
        STG(Bs0, gb, 128, kb2); STG(Bs0, gb, 192, kb2);
        MFMA16(2);
        LDA_QUAD(As0, 3);
        MFMA16(3);
        VM4;   // retires B(t+1)+A(t+1) (read in Ph3); B(t+2) stays in flight
        BAR;   // frees As0; globalizes B(t+1)/A(t+1)

        // ---- Ph3: tile t+1 (buf1): B all + A quad0; stage A(t+2)->buf0 ----
        LDB_ALL(Bs1); LDA_QUAD(As1, 0);
        STG(As0, ga, 0, kb2); STG(As0, ga, 64, kb2);
        STG(As0, ga, 128, kb2); STG(As0, ga, 192, kb2);
        MFMA16(0);
        BAR;   // frees Bs1

        // ---- Ph4: A quads 1-3; stage B(t+3)->Bs1; 48 MFMAs; VM4 ----
        LDA_QUAD(As1, 1);
        STG(Bs1, gb, 0, kb3); STG(Bs1, gb, 64, kb3);
        MFMA16(1);
        LDA_QUAD(As1, 2);
        STG(Bs1, gb, 128, kb3); STG(Bs1, gb, 192, kb3);
        MFMA16(2);
        LDA_QUAD(As1, 3);
        MFMA16(3);
        VM4;   // retires B(t+2)+A(t+2) (read next iter Ph1); B(t+3) in flight
        BAR;   // frees As1; globalizes B(t+2)/A(t+2)
    }

    // ---- epilogue: C/D layout col=lane&15, row=quad*4+reg (verified) ----
#pragma unroll
    for (int j = 0; j < 4; ++j) {
        const int col = n0 + wn * 64 + j * 16 + l16;
        const float bj = bias[col];
#pragma unroll
        for (int f = 0; f < 8; ++f) {
            const int rowb = m0 + wm * 128 + f * 16 + quad * 4;
#pragma unroll
            for (int r = 0; r < 4; ++r)
                out[(size_t)(rowb + r) * NDIM + col] = acc[f][j][r] + bj;
        }
    }

#undef STG
#undef BAR
#undef VM4
#undef LDA_QUAD
#undef LDB_ALL
#undef MFMA16
}

extern "C" void kernel_launch(void* const* d_in, const int* in_sizes, int n_in,
                              void* d_out, int out_size, void* d_ws, size_t ws_size,
                              hipStream_t stream) {
    const float* x    = (const float*)d_in[0];   // [8,2048,2048]
    const float* W    = (const float*)d_in[1];   // [2048,2048] row-major [o,d]
    const float* bias = (const float*)d_in[2];   // [2048]
    const float* Bm   = (const float*)d_in[3];   // [2048,16]
    const float* Am   = (const float*)d_in[4];   // [16,2048]
    float* out = (float*)d_out;

    u16* xb   = (u16*)d_ws;                      // 16384*2048 bf16 = 64 MB
    u16* wbuf = xb + (size_t)MDIM * KDIM;        // 2048*2048 bf16 = 8 MB

    prep<<<PREP_BLOCKS, 256, 0, stream>>>(x, W, Bm, Am, xb, wbuf);

    dim3 grid((MDIM / BM) * (NDIM / BN));        // 512 blocks
    gemm_bt<<<grid, 512, 0, stream>>>(xb, wbuf, bias, out);
}